// Round 7
// baseline (197.465 us; speedup 1.0000x reference)
//
#include <hip/hip_runtime.h>
#include <hip/hip_bf16.h>

// Problem constants
#define D 128
#define EPS 1e-5f

typedef __bf16 bf16x8 __attribute__((ext_vector_type(8)));
typedef __bf16 bf16x4 __attribute__((ext_vector_type(4)));
typedef float  f32x4  __attribute__((ext_vector_type(4)));

// ---------------------------------------------------------------------------
// Kernel 1 (prep): convert W (f32) -> Wb (bf16, 32 KB) once, plus the
// dst-degree histogram. Both tiny; one launch. counts must be pre-zeroed.
// ---------------------------------------------------------------------------
__global__ __launch_bounds__(256) void prep_kernel(
    const float* __restrict__ W, __bf16* __restrict__ Wb,
    const int* __restrict__ e, int* __restrict__ counts, int E)
{
    const int tid = blockIdx.x * 256 + threadIdx.x;

    // W convert: 128x128 f32 = 4096 float4 -> bf16x4 (8 B) stores
    if (tid < 4096) {
        float4 v = ((const float4*)W)[tid];
        bf16x4 h;
        h[0] = (__bf16)v.x; h[1] = (__bf16)v.y;
        h[2] = (__bf16)v.z; h[3] = (__bf16)v.w;
        ((bf16x4*)Wb)[tid] = h;
    }

    // Histogram: grid-stride; fire-and-forget atomics
    const int stride = gridDim.x * 256;
    for (int i = tid; i < E; i += stride)
        atomicAdd(&counts[e[2 * i + 1]], 1);
}

// ---------------------------------------------------------------------------
// Kernel 2: y_bf16 = relu(x @ W^T + b) via MFMA, LDS-FREE.
// 256 threads = 4 waves; wave w owns rows blockIdx*64 + w*16 .. +15.
// A-frag: lane l loads x[row0+(l&15)][ks*32+(l>>4)*8 ..+7] f32 direct from
//   global (each row read exactly once -> LDS staging buys nothing) and
//   converts to bf16 in registers.
// B-frag: lane l loads Wb[ct*16+(l&15)][ks*32+(l>>4)*8 ..+7] direct from
//   global; Wb is 32 KB -> L1/L2-resident across all 2500 waves.
// C/D layout (m89-verified): col = lane&15, row = (lane>>4)*4 + reg.
// Only one f32x4 acc live at a time -> low VGPR, high occupancy, no barriers.
// ---------------------------------------------------------------------------
__global__ __launch_bounds__(256) void gemm_kernel(
    const float* __restrict__ x, const __bf16* __restrict__ Wb,
    const float* __restrict__ b, __bf16* __restrict__ y, int n)
{
    const int tid  = threadIdx.x;
    const int w    = tid >> 6;
    const int l    = tid & 63;
    const int lr   = l & 15;
    const int lk   = l >> 4;                 // 0..3
    const int row0 = blockIdx.x * 64 + w * 16;

    // A-row this lane reads (clamped; results masked at store)
    int ar = row0 + lr;
    if (ar >= n) ar = n - 1;
    const float* xr = x + (size_t)ar * D;

    bf16x8 a[4];
#pragma unroll
    for (int ks = 0; ks < 4; ks++) {
        float4 v0 = *(const float4*)(xr + ks * 32 + lk * 8);
        float4 v1 = *(const float4*)(xr + ks * 32 + lk * 8 + 4);
        bf16x8 t;
        t[0] = (__bf16)v0.x; t[1] = (__bf16)v0.y;
        t[2] = (__bf16)v0.z; t[3] = (__bf16)v0.w;
        t[4] = (__bf16)v1.x; t[5] = (__bf16)v1.y;
        t[6] = (__bf16)v1.z; t[7] = (__bf16)v1.w;
        a[ks] = t;
    }

#pragma unroll
    for (int ct = 0; ct < 8; ct++) {
        f32x4 acc = {0.f, 0.f, 0.f, 0.f};
#pragma unroll
        for (int ks = 0; ks < 4; ks++) {
            bf16x8 bf = *(const bf16x8*)(Wb + (ct * 16 + lr) * D + ks * 32 + lk * 8);
            acc = __builtin_amdgcn_mfma_f32_16x16x32_bf16(a[ks], bf, acc, 0, 0, 0);
        }
        const int col  = ct * 16 + lr;
        const float bias = b[col];
        const int gr0  = row0 + lk * 4;
#pragma unroll
        for (int reg = 0; reg < 4; reg++) {
            int gr = gr0 + reg;
            if (gr < n)
                y[(size_t)gr * D + col] = (__bf16)fmaxf(acc[reg] + bias, 0.f);
        }
    }
}

// ---------------------------------------------------------------------------
// CSR build, step 2a: per-block exclusive scan (256 elems/block).
// Relative exclusive offsets -> row_start; block totals -> partials.
// ---------------------------------------------------------------------------
__global__ __launch_bounds__(256) void scan_partial_kernel(
    const int* __restrict__ counts, int* __restrict__ row_start,
    int* __restrict__ partials, int n)
{
    __shared__ int s[256];
    const int tid = threadIdx.x;
    const int i = blockIdx.x * 256 + tid;
    int v = (i < n) ? counts[i] : 0;
    s[tid] = v;
    __syncthreads();
    for (int off = 1; off < 256; off <<= 1) {
        int add = (tid >= off) ? s[tid - off] : 0;
        __syncthreads();
        s[tid] += add;
        __syncthreads();
    }
    if (i < n) row_start[i] = s[tid] - v;        // relative exclusive
    if (tid == 255) partials[blockIdx.x] = s[255];
}

// ---------------------------------------------------------------------------
// CSR build, step 2b (merged): every block re-scans the partials in LDS,
// takes its own exclusive prefix, and adds it to its 256 rows. nb <= 256.
// ---------------------------------------------------------------------------
__global__ __launch_bounds__(256) void scan_add_kernel(
    int* __restrict__ row_start, const int* __restrict__ partials,
    int* __restrict__ cursor, int n, int nb)
{
    __shared__ int s[256];
    const int tid = threadIdx.x;
    int v = (tid < nb) ? partials[tid] : 0;
    s[tid] = v;
    __syncthreads();
    for (int off = 1; off < 256; off <<= 1) {
        int add = (tid >= off) ? s[tid - off] : 0;
        __syncthreads();
        s[tid] += add;
        __syncthreads();
    }
    int off0 = (blockIdx.x == 0) ? 0 : s[blockIdx.x - 1];  // exclusive prefix

    int i = blockIdx.x * 256 + tid;
    if (i < n) {
        int val = row_start[i] + off0;
        row_start[i] = val;
        cursor[i]    = val;
    }
}

// ---------------------------------------------------------------------------
// CSR build, step 3: place each edge's src into its dst segment.
// Placement order nondeterministic; max is order-independent -> bit-exact.
// ---------------------------------------------------------------------------
__global__ __launch_bounds__(256) void place_kernel(
    const int* __restrict__ e, int* __restrict__ cursor,
    int* __restrict__ sorted_src, int E)
{
    int i = blockIdx.x * 256 + threadIdx.x;
    if (i < E) {
        int2 ed = ((const int2*)e)[i];             // (src, dst)
        int pos = atomicAdd(&cursor[ed.y], 1);
        sorted_src[pos] = ed.x;
    }
}

// ---------------------------------------------------------------------------
// Kernel 5 (fused): per-dst gather-max over CSR segment (y in bf16), then
// h = x + agg; RMSNorm; out = h * rsqrt(mean(h^2)+eps) * g + rb.
// One 64-lane wave per row; each lane holds one uint = 2 bf16 (256 B/row
// coalesced gather). bf16 -> f32 is an exact <<16; max over bf16 is exact.
// Unroll-4 for memory-level parallelism. Empty segment -> agg = 0.
// ---------------------------------------------------------------------------
__global__ __launch_bounds__(256) void seg_max_finalize_kernel(
    const int* __restrict__ row_start, const int* __restrict__ counts,
    const int* __restrict__ sorted_src, const unsigned int* __restrict__ ybu,
    const float* __restrict__ x, const float* __restrict__ g,
    const float* __restrict__ rb, float* __restrict__ out, int n)
{
    int row  = blockIdx.x * 4 + (threadIdx.x >> 6);
    int lane = threadIdx.x & 63;
    if (row >= n) return;

    const int start = row_start[row];
    const int cnt   = counts[row];

    float mx = 0.f, my = 0.f;
    int k = 0;
    for (; k + 3 < cnt; k += 4) {
        int s0 = sorted_src[start + k];
        int s1 = sorted_src[start + k + 1];
        int s2 = sorted_src[start + k + 2];
        int s3 = sorted_src[start + k + 3];
        unsigned int u0 = ybu[(size_t)s0 * 64 + lane];
        unsigned int u1 = ybu[(size_t)s1 * 64 + lane];
        unsigned int u2 = ybu[(size_t)s2 * 64 + lane];
        unsigned int u3 = ybu[(size_t)s3 * 64 + lane];
        mx = fmaxf(mx, fmaxf(fmaxf(__uint_as_float(u0 << 16),
                                   __uint_as_float(u1 << 16)),
                             fmaxf(__uint_as_float(u2 << 16),
                                   __uint_as_float(u3 << 16))));
        my = fmaxf(my, fmaxf(fmaxf(__uint_as_float(u0 & 0xffff0000u),
                                   __uint_as_float(u1 & 0xffff0000u)),
                             fmaxf(__uint_as_float(u2 & 0xffff0000u),
                                   __uint_as_float(u3 & 0xffff0000u))));
    }
    for (; k < cnt; k++) {
        int s0 = sorted_src[start + k];
        unsigned int u0 = ybu[(size_t)s0 * 64 + lane];
        mx = fmaxf(mx, __uint_as_float(u0 << 16));
        my = fmaxf(my, __uint_as_float(u0 & 0xffff0000u));
    }

    float2 xv = ((const float2*)(x + (size_t)row * D))[lane];
    float hx = xv.x + mx;
    float hy = xv.y + my;

    float ss = hx * hx + hy * hy;
#pragma unroll
    for (int off = 1; off < 64; off <<= 1) ss += __shfl_xor(ss, off);

    float inv = rsqrtf(ss * (1.0f / (float)D) + EPS);

    float2 gv = ((const float2*)g)[lane];
    float2 rv = ((const float2*)rb)[lane];
    float2 o  = make_float2(hx * inv * gv.x + rv.x,
                            hy * inv * gv.y + rv.y);
    ((float2*)(out + (size_t)row * D))[lane] = o;
}

// ---------------------------------------------------------------------------
extern "C" void kernel_launch(void* const* d_in, const int* in_sizes, int n_in,
                              void* d_out, int out_size, void* d_ws, size_t ws_size,
                              hipStream_t stream)
{
    const float* x  = (const float*)d_in[0];
    const int*   e  = (const int*)  d_in[1];
    const float* W  = (const float*)d_in[2];
    const float* b  = (const float*)d_in[3];
    const float* g  = (const float*)d_in[4];
    const float* rb = (const float*)d_in[5];
    float* out = (float*)d_out;

    const int n = in_sizes[0] / D;     // 40000 nodes
    const int E = in_sizes[1] / 2;     // 640000 edges

    // Workspace layout
    char* ws = (char*)d_ws;
    __bf16* y        = (__bf16*)(ws);               // 10,240,000 B
    int*   counts    = (int*)  (ws + 10240000);     //    160,000 B
    int*   row_start = (int*)  (ws + 10400000);     //    160,000 B
    int*   cursor    = (int*)  (ws + 10560000);     //    160,000 B
    int*   sorted_src= (int*)  (ws + 10720000);     //  2,560,000 B
    int*   partials  = (int*)  (ws + 13280000);     //      1,024 B
    __bf16* Wb       = (__bf16*)(ws + 13281280);    //     32,768 B

    const int nb = (n + 255) / 256;                 // 157 (must be <= 256)

    hipMemsetAsync(counts, 0, (size_t)n * sizeof(int), stream);

    prep_kernel<<<640, 256, 0, stream>>>(W, Wb, e, counts, E);

    gemm_kernel<<<(n + 63) / 64, 256, 0, stream>>>(x, Wb, b, y, n);

    scan_partial_kernel<<<nb, 256, 0, stream>>>(counts, row_start, partials, n);
    scan_add_kernel<<<nb, 256, 0, stream>>>(row_start, partials, cursor, n, nb);
    place_kernel<<<(E + 255) / 256, 256, 0, stream>>>(e, cursor, sorted_src, E);

    seg_max_finalize_kernel<<<(n + 3) / 4, 256, 0, stream>>>(
        row_start, counts, sorted_src, (const unsigned int*)y, x, g, rb, out, n);
}

// Round 8
// 189.013 us; speedup vs baseline: 1.0447x; 1.0447x over previous
//
#include <hip/hip_runtime.h>
#include <hip/hip_bf16.h>

// Problem constants
#define D 128
#define EPS 1e-5f

typedef __bf16 bf16x8 __attribute__((ext_vector_type(8)));
typedef __bf16 bf16x4 __attribute__((ext_vector_type(4)));
typedef float  f32x4  __attribute__((ext_vector_type(4)));

// ---------------------------------------------------------------------------
// Kernel 1 (prep): convert W (f32) -> Wb (bf16, 32 KB) AND zero counts.
// 16 blocks x 256 = 4096 threads: 1 float4 of W each, 10 counts each.
// Replaces the hipMemsetAsync node (stream order guarantees counts are
// zeroed before gemm's fused histogram runs).
// ---------------------------------------------------------------------------
__global__ __launch_bounds__(256) void prep_kernel(
    const float* __restrict__ W, __bf16* __restrict__ Wb,
    int* __restrict__ counts, int n)
{
    const int tid = blockIdx.x * 256 + threadIdx.x;   // 0..4095

    if (tid < 4096) {
        float4 v = ((const float4*)W)[tid];
        bf16x4 h;
        h[0] = (__bf16)v.x; h[1] = (__bf16)v.y;
        h[2] = (__bf16)v.z; h[3] = (__bf16)v.w;
        ((bf16x4*)Wb)[tid] = h;
    }
    for (int i = tid; i < n; i += 4096)
        counts[i] = 0;
}

// ---------------------------------------------------------------------------
// Kernel 2 (fused): y_bf16 = relu(x @ W^T + b) via MFMA + dst histogram.
// 256 threads = 4 waves; block tile = 64 rows x 128 cols, K=128 one shot.
// x staged in LDS as f32 via coalesced float4 (33.8 KB -> 4 blocks/CU);
// fragments converted to bf16 in registers after ds_read. W read directly
// from global bf16 (32 KB, L1-resident). Histogram atomics issued between
// staging and barrier so their latency hides under the MFMA pipeline.
// C/D layout (m89-verified): col = lane&15, row = (lane>>4)*4 + reg.
// ---------------------------------------------------------------------------
__global__ __launch_bounds__(256) void gemm_kernel(
    const float* __restrict__ x, const __bf16* __restrict__ Wb,
    const float* __restrict__ b, __bf16* __restrict__ y,
    const int* __restrict__ e, int* __restrict__ counts,
    int n, int E)
{
    __shared__ __attribute__((aligned(16))) float xs[64][132];

    const int tid  = threadIdx.x;
    const int row0b = blockIdx.x * 64;

    // Coalesced f32 staging: 2048 float4, 8 per thread, no conversion.
    for (int i = tid; i < 2048; i += 256) {
        int r = i >> 5, q = i & 31;
        int gr = row0b + r;
        float4 v = make_float4(0.f, 0.f, 0.f, 0.f);
        if (gr < n) v = ((const float4*)x)[(size_t)gr * 32 + q];
        *(float4*)&xs[r][q * 4] = v;
    }

    // Fused histogram: grid-stride over E (625*256 threads -> 4 edges each).
    {
        const int base   = blockIdx.x * 256 + tid;
        const int stride = gridDim.x * 256;
        for (int i = base; i < E; i += stride)
            atomicAdd(&counts[e[2 * i + 1]], 1);
    }
    __syncthreads();

    const int w  = tid >> 6;
    const int l  = tid & 63;
    const int lr = l & 15;
    const int lk = l >> 4;                 // 0..3
    const int row0 = row0b + w * 16;

    // A-frags from LDS, convert f32 -> bf16 in registers
    bf16x8 a[4];
#pragma unroll
    for (int ks = 0; ks < 4; ks++) {
        const float* p = &xs[w * 16 + lr][ks * 32 + lk * 8];
        float4 v0 = *(const float4*)p;
        float4 v1 = *(const float4*)(p + 4);
        bf16x8 t;
        t[0] = (__bf16)v0.x; t[1] = (__bf16)v0.y;
        t[2] = (__bf16)v0.z; t[3] = (__bf16)v0.w;
        t[4] = (__bf16)v1.x; t[5] = (__bf16)v1.y;
        t[6] = (__bf16)v1.z; t[7] = (__bf16)v1.w;
        a[ks] = t;
    }

#pragma unroll
    for (int ct = 0; ct < 8; ct++) {
        f32x4 acc = {0.f, 0.f, 0.f, 0.f};
#pragma unroll
        for (int ks = 0; ks < 4; ks++) {
            bf16x8 bf = *(const bf16x8*)(Wb + (ct * 16 + lr) * D + ks * 32 + lk * 8);
            acc = __builtin_amdgcn_mfma_f32_16x16x32_bf16(a[ks], bf, acc, 0, 0, 0);
        }
        const int col  = ct * 16 + lr;
        const float bias = b[col];
        const int gr0  = row0 + lk * 4;
#pragma unroll
        for (int reg = 0; reg < 4; reg++) {
            int gr = gr0 + reg;
            if (gr < n)
                y[(size_t)gr * D + col] = (__bf16)fmaxf(acc[reg] + bias, 0.f);
        }
    }
}

// ---------------------------------------------------------------------------
// CSR build, step 2a: per-block exclusive scan (256 elems/block).
// Relative exclusive offsets -> row_start; block totals -> partials.
// ---------------------------------------------------------------------------
__global__ __launch_bounds__(256) void scan_partial_kernel(
    const int* __restrict__ counts, int* __restrict__ row_start,
    int* __restrict__ partials, int n)
{
    __shared__ int s[256];
    const int tid = threadIdx.x;
    const int i = blockIdx.x * 256 + tid;
    int v = (i < n) ? counts[i] : 0;
    s[tid] = v;
    __syncthreads();
    for (int off = 1; off < 256; off <<= 1) {
        int add = (tid >= off) ? s[tid - off] : 0;
        __syncthreads();
        s[tid] += add;
        __syncthreads();
    }
    if (i < n) row_start[i] = s[tid] - v;        // relative exclusive
    if (tid == 255) partials[blockIdx.x] = s[255];
}

// ---------------------------------------------------------------------------
// CSR build, step 2b (merged): every block re-scans the partials in LDS,
// takes its own exclusive prefix, and adds it to its 256 rows. nb <= 256.
// Also writes the CSR sentinel row_start[n] = E (total).
// ---------------------------------------------------------------------------
__global__ __launch_bounds__(256) void scan_add_kernel(
    int* __restrict__ row_start, const int* __restrict__ partials,
    int* __restrict__ cursor, int n, int nb)
{
    __shared__ int s[256];
    const int tid = threadIdx.x;
    int v = (tid < nb) ? partials[tid] : 0;
    s[tid] = v;
    __syncthreads();
    for (int off = 1; off < 256; off <<= 1) {
        int add = (tid >= off) ? s[tid - off] : 0;
        __syncthreads();
        s[tid] += add;
        __syncthreads();
    }
    int off0 = (blockIdx.x == 0) ? 0 : s[blockIdx.x - 1];  // exclusive prefix

    if (blockIdx.x == 0 && tid == 0)
        row_start[n] = s[255];                    // sentinel: total edge count

    int i = blockIdx.x * 256 + tid;
    if (i < n) {
        int val = row_start[i] + off0;
        row_start[i] = val;
        cursor[i]    = val;
    }
}

// ---------------------------------------------------------------------------
// CSR build, step 3: place each edge's src (fits uint16: n<65536) into its
// dst segment. Order nondeterministic; max is order-independent -> bit-exact.
// ---------------------------------------------------------------------------
__global__ __launch_bounds__(256) void place_kernel(
    const int* __restrict__ e, int* __restrict__ cursor,
    unsigned short* __restrict__ sorted_src, int E)
{
    int i = blockIdx.x * 256 + threadIdx.x;
    if (i < E) {
        int2 ed = ((const int2*)e)[i];             // (src, dst)
        int pos = atomicAdd(&cursor[ed.y], 1);
        sorted_src[pos] = (unsigned short)ed.x;
    }
}

// ---------------------------------------------------------------------------
// Kernel 5 (fused): per-dst gather-max over CSR segment (y in bf16), then
// h = x + agg; RMSNorm; out = h * rsqrt(mean(h^2)+eps) * g + rb.
// One 64-lane wave per row; lane holds one uint = 2 bf16 (256 B/row gather).
// bf16 -> f32 is an exact <<16; max over non-negative bf16 is exact.
// Unroll-8 for gather MLP. Empty segment -> agg = 0 (deg==0 semantics).
// ---------------------------------------------------------------------------
__global__ __launch_bounds__(256) void seg_max_finalize_kernel(
    const int* __restrict__ row_start, const unsigned short* __restrict__ ssrc,
    const unsigned int* __restrict__ ybu, const float* __restrict__ x,
    const float* __restrict__ g, const float* __restrict__ rb,
    float* __restrict__ out, int n)
{
    int row  = blockIdx.x * 4 + (threadIdx.x >> 6);
    int lane = threadIdx.x & 63;
    if (row >= n) return;

    const int start = row_start[row];
    const int end   = row_start[row + 1];

    float mx = 0.f, my = 0.f;
    int k = start;
    const int end8 = start + ((end - start) & ~7);
    for (; k < end8; k += 8) {
        unsigned int u0, u1, u2, u3, u4, u5, u6, u7;
        {
            int s0 = ssrc[k + 0], s1 = ssrc[k + 1], s2 = ssrc[k + 2], s3 = ssrc[k + 3];
            int s4 = ssrc[k + 4], s5 = ssrc[k + 5], s6 = ssrc[k + 6], s7 = ssrc[k + 7];
            u0 = ybu[(size_t)s0 * 64 + lane];
            u1 = ybu[(size_t)s1 * 64 + lane];
            u2 = ybu[(size_t)s2 * 64 + lane];
            u3 = ybu[(size_t)s3 * 64 + lane];
            u4 = ybu[(size_t)s4 * 64 + lane];
            u5 = ybu[(size_t)s5 * 64 + lane];
            u6 = ybu[(size_t)s6 * 64 + lane];
            u7 = ybu[(size_t)s7 * 64 + lane];
        }
        mx = fmaxf(mx, fmaxf(fmaxf(__uint_as_float(u0 << 16), __uint_as_float(u1 << 16)),
                             fmaxf(__uint_as_float(u2 << 16), __uint_as_float(u3 << 16))));
        mx = fmaxf(mx, fmaxf(fmaxf(__uint_as_float(u4 << 16), __uint_as_float(u5 << 16)),
                             fmaxf(__uint_as_float(u6 << 16), __uint_as_float(u7 << 16))));
        my = fmaxf(my, fmaxf(fmaxf(__uint_as_float(u0 & 0xffff0000u), __uint_as_float(u1 & 0xffff0000u)),
                             fmaxf(__uint_as_float(u2 & 0xffff0000u), __uint_as_float(u3 & 0xffff0000u))));
        my = fmaxf(my, fmaxf(fmaxf(__uint_as_float(u4 & 0xffff0000u), __uint_as_float(u5 & 0xffff0000u)),
                             fmaxf(__uint_as_float(u6 & 0xffff0000u), __uint_as_float(u7 & 0xffff0000u))));
    }
    for (; k < end; k++) {
        int s0 = ssrc[k];
        unsigned int u0 = ybu[(size_t)s0 * 64 + lane];
        mx = fmaxf(mx, __uint_as_float(u0 << 16));
        my = fmaxf(my, __uint_as_float(u0 & 0xffff0000u));
    }

    float2 xv = ((const float2*)(x + (size_t)row * D))[lane];
    float hx = xv.x + mx;
    float hy = xv.y + my;

    float ss = hx * hx + hy * hy;
#pragma unroll
    for (int off = 1; off < 64; off <<= 1) ss += __shfl_xor(ss, off);

    float inv = rsqrtf(ss * (1.0f / (float)D) + EPS);

    float2 gv = ((const float2*)g)[lane];
    float2 rv = ((const float2*)rb)[lane];
    float2 o  = make_float2(hx * inv * gv.x + rv.x,
                            hy * inv * gv.y + rv.y);
    ((float2*)(out + (size_t)row * D))[lane] = o;
}

// ---------------------------------------------------------------------------
extern "C" void kernel_launch(void* const* d_in, const int* in_sizes, int n_in,
                              void* d_out, int out_size, void* d_ws, size_t ws_size,
                              hipStream_t stream)
{
    const float* x  = (const float*)d_in[0];
    const int*   e  = (const int*)  d_in[1];
    const float* W  = (const float*)d_in[2];
    const float* b  = (const float*)d_in[3];
    const float* g  = (const float*)d_in[4];
    const float* rb = (const float*)d_in[5];
    float* out = (float*)d_out;

    const int n = in_sizes[0] / D;     // 40000 nodes
    const int E = in_sizes[1] / 2;     // 640000 edges

    // Workspace layout (256B-aligned offsets)
    char* ws = (char*)d_ws;
    __bf16* y        = (__bf16*)(ws);                      // 10,240,000 B
    int*   counts    = (int*)  (ws + 10240000);            //    160,000 B
    int*   row_start = (int*)  (ws + 10400000);            //    160,004 B (+sentinel)
    int*   cursor    = (int*)  (ws + 10560256);            //    160,000 B
    unsigned short* sorted_src = (unsigned short*)(ws + 10720256); // 1,280,000 B
    int*   partials  = (int*)  (ws + 12000256);            //      1,024 B
    __bf16* Wb       = (__bf16*)(ws + 12001536);           //     32,768 B

    const int nb = (n + 255) / 256;                 // 157 (must be <= 256)

    prep_kernel<<<16, 256, 0, stream>>>(W, Wb, counts, n);

    gemm_kernel<<<(n + 63) / 64, 256, 0, stream>>>(x, Wb, b, y, e, counts, n, E);

    scan_partial_kernel<<<nb, 256, 0, stream>>>(counts, row_start, partials, n);
    scan_add_kernel<<<nb, 256, 0, stream>>>(row_start, partials, cursor, n, nb);
    place_kernel<<<(E + 255) / 256, 256, 0, stream>>>(e, cursor, sorted_src, E);

    seg_max_finalize_kernel<<<(n + 3) / 4, 256, 0, stream>>>(
        row_start, sorted_src, (const unsigned int*)y, x, g, rb, out, n);
}